// Round 2
// baseline (433.022 us; speedup 1.0000x reference)
//
#include <hip/hip_runtime.h>
#include <hip/hip_bf16.h>

#define N_Q   16384
#define C_DIM 128
#define S_CAM 6
#define M_VAL 1400   // 28*50
#define D_Z   8
#define HF    28
#define WF    50

// ---------------------------------------------------------------------------
// Determine how the bool bev_mask was uploaded: 0=uint8, 1=int32, 2=int64.
// Random 0/1 bools: uint8 -> bytes at i%4!=0 ~50% nonzero; int32 -> those are
// zero but i%8==4 bytes ~50% nonzero; int64 -> both groups all zero.
// ---------------------------------------------------------------------------
__global__ void sniff_mask_kernel(const unsigned char* __restrict__ m,
                                  int* __restrict__ flag){
  __shared__ int cntA, cntB;
  if(threadIdx.x==0){ cntA=0; cntB=0; }
  __syncthreads();
  int i = threadIdx.x;            // mask buffer is >= 1024 bytes in all layouts
  unsigned char v = m[i];
  if(((i&3)!=0) && v!=0) atomicAdd(&cntA,1);
  if(((i&7)==4) && v!=0) atomicAdd(&cntB,1);
  __syncthreads();
  if(threadIdx.x==0) *flag = (cntA>0) ? 0 : (cntB>0 ? 1 : 2);
}

__device__ __forceinline__ bool mask_any(const unsigned char* __restrict__ mask,
                                         int mflag, size_t mbase){
  if(mflag==0){
    int any=0;
    #pragma unroll
    for(int d=0;d<D_Z;d++) any |= mask[mbase+d];
    return any!=0;
  } else if(mflag==1){
    const int* mp = (const int*)mask;  int any=0;
    #pragma unroll
    for(int d=0;d<D_Z;d++) any |= mp[mbase+d];
    return any!=0;
  } else {
    const long long* mp = (const long long*)mask;  long long any=0;
    #pragma unroll
    for(int d=0;d<D_Z;d++) any |= mp[mbase+d];
    return any!=0;
  }
}

// ---------------------------------------------------------------------------
// v = value @ Wv + bv   (8400 x 128) @ (128 x 128), f32 -> workspace.
// Block = 16 rows, 128 threads (thread = output column).
// ---------------------------------------------------------------------------
__global__ void value_proj_kernel(const float* __restrict__ value,
                                  const float* __restrict__ Wv,
                                  const float* __restrict__ bv,
                                  float* __restrict__ vout){
  __shared__ float tile[16][C_DIM];
  const int r0  = blockIdx.x * 16;
  const int tid = threadIdx.x;
  #pragma unroll
  for(int r=0;r<16;r++)
    tile[r][tid] = value[(size_t)(r0+r)*C_DIM + tid];
  __syncthreads();
  float acc[16];
  const float bias = bv[tid];
  #pragma unroll
  for(int r=0;r<16;r++) acc[r]=bias;
  for(int k=0;k<C_DIM;k++){
    const float w = Wv[k*C_DIM + tid];
    #pragma unroll
    for(int r=0;r<16;r++) acc[r] += tile[r][k]*w;   // tile[r][k]: LDS broadcast
  }
  #pragma unroll
  for(int r=0;r<16;r++)
    vout[(size_t)(r0+r)*C_DIM + tid] = acc[r];
}

// ---------------------------------------------------------------------------
// Path A: q = query+query_pos; off = q@Wo+bo (N x 64);
// attn = softmax_P(q@Wa+ba) (N x 32). q identical across cameras -> once.
// ---------------------------------------------------------------------------
__global__ void q_proj_kernel(const float* __restrict__ query,
                              const float* __restrict__ query_pos,
                              const float* __restrict__ Wo, const float* __restrict__ bo,
                              const float* __restrict__ Wa, const float* __restrict__ ba,
                              float* __restrict__ off_out,
                              float* __restrict__ attn_out){
  __shared__ float qt[16][C_DIM];
  __shared__ float logits[16][32];
  const int n0  = blockIdx.x * 16;
  const int tid = threadIdx.x;
  #pragma unroll
  for(int r=0;r<16;r++){
    const size_t idx = (size_t)(n0+r)*C_DIM + tid;
    qt[r][tid] = query[idx] + query_pos[idx];
  }
  __syncthreads();
  if(tid < 96){
    const bool isOff = (tid < 64);
    const int  col   = isOff ? tid : tid-64;
    float acc[16];
    const float bias = isOff ? bo[col] : ba[col];
    #pragma unroll
    for(int r=0;r<16;r++) acc[r]=bias;
    for(int k=0;k<C_DIM;k++){
      const float w = isOff ? Wo[k*64+col] : Wa[k*32+col];
      #pragma unroll
      for(int r=0;r<16;r++) acc[r] += qt[r][k]*w;
    }
    if(isOff){
      #pragma unroll
      for(int r=0;r<16;r++) off_out[(size_t)(n0+r)*64 + col] = acc[r];
    } else {
      #pragma unroll
      for(int r=0;r<16;r++) logits[r][col] = acc[r];
    }
  }
  __syncthreads();
  if(tid < 64){                       // 16 rows x 4 heads
    const int r = tid >> 2, h = tid & 3;
    const float* L = &logits[r][h*8];
    float mx = L[0];
    #pragma unroll
    for(int p=1;p<8;p++) mx = fmaxf(mx, L[p]);
    float e[8], ssum = 0.f;
    #pragma unroll
    for(int p=0;p<8;p++){ e[p] = __expf(L[p]-mx); ssum += e[p]; }
    const float inv = 1.f/ssum;
    #pragma unroll
    for(int p=0;p<8;p++) attn_out[(size_t)(n0+r)*32 + h*8 + p] = e[p]*inv;
  }
}

// ---------------------------------------------------------------------------
// Bilinear gather + camera-masked average for one query (block), thread =
// channel (h = tid>>5). INLINE_Q: also compute off/attn in-block (small-ws
// fallback). Otherwise read them from workspace and write slots (path A).
// ---------------------------------------------------------------------------
template<bool INLINE_Q>
__global__ void deform_kernel(const float* __restrict__ vproj,
                              const float* __restrict__ off,
                              const float* __restrict__ attnw,
                              const float* __restrict__ query,
                              const float* __restrict__ query_pos,
                              const float* __restrict__ Wo, const float* __restrict__ bo,
                              const float* __restrict__ Wa, const float* __restrict__ ba,
                              const float* __restrict__ ref,
                              const unsigned char* __restrict__ mask,
                              const int* __restrict__ flag,
                              const float* __restrict__ Wout,
                              const float* __restrict__ bout,
                              float* __restrict__ slots_or_out){
  __shared__ float offs[64];
  __shared__ float attns[32];
  __shared__ float qs[C_DIM];
  __shared__ float logits[32];
  __shared__ float sl[C_DIM];

  const int n   = blockIdx.x;
  const int tid = threadIdx.x;
  const int h   = tid >> 5;
  const int mflag = flag[0];

  if(INLINE_Q){
    qs[tid] = query[(size_t)n*C_DIM + tid] + query_pos[(size_t)n*C_DIM + tid];
    __syncthreads();
    if(tid < 96){
      const bool isOff = (tid < 64);
      const int  col   = isOff ? tid : tid-64;
      float acc = isOff ? bo[col] : ba[col];
      for(int k=0;k<C_DIM;k++)
        acc += qs[k] * (isOff ? Wo[k*64+col] : Wa[k*32+col]);
      if(isOff) offs[col] = acc; else logits[col] = acc;
    }
    __syncthreads();
    if(tid < 4){
      const float* L = &logits[tid*8];
      float mx = L[0];
      #pragma unroll
      for(int p=1;p<8;p++) mx = fmaxf(mx, L[p]);
      float e[8], ssum=0.f;
      #pragma unroll
      for(int p=0;p<8;p++){ e[p]=__expf(L[p]-mx); ssum+=e[p]; }
      const float inv = 1.f/ssum;
      #pragma unroll
      for(int p=0;p<8;p++) attns[tid*8+p] = e[p]*inv;
    }
    __syncthreads();
  } else {
    if(tid < 64)              offs[tid]      = off[(size_t)n*64 + tid];
    else if(tid < 96)         attns[tid-64]  = attnw[(size_t)n*32 + (tid-64)];
    __syncthreads();
  }

  float acc = 0.f, cnt = 0.f;
  for(int s=0;s<S_CAM;s++){
    const size_t mbase = ((size_t)s*N_Q + n)*D_Z;
    if(!mask_any(mask, mflag, mbase)) continue;
    cnt += 1.f;
    const float* rp = ref + mbase*2;
    const float* vb = vproj + (size_t)s*M_VAL*C_DIM;
    float a = 0.f;
    #pragma unroll
    for(int p=0;p<8;p++){                     // point p <-> z-anchor d=p (P//D==1)
      const float x = (rp[p*2+0] + offs[h*16+p*2+0]*(1.0f/(float)WF)) * (float)WF - 0.5f;
      const float y = (rp[p*2+1] + offs[h*16+p*2+1]*(1.0f/(float)HF)) * (float)HF - 0.5f;
      const float x0f = floorf(x), y0f = floorf(y);
      const float fx = x - x0f,    fy = y - y0f;
      const int x0 = (int)x0f, y0 = (int)y0f;
      const int x1 = x0+1,     y1 = y0+1;
      const bool vx0 = (x0>=0)&(x0<WF), vx1 = (x1>=0)&(x1<WF);
      const bool vy0 = (y0>=0)&(y0<HF), vy1 = (y1>=0)&(y1<HF);
      float g = 0.f;
      if(vy0){
        const float* row = vb + (size_t)(y0*WF)*C_DIM;
        if(vx0) g += (1.f-fx)*(1.f-fy) * row[x0*C_DIM + tid];
        if(vx1) g += fx*(1.f-fy)       * row[x1*C_DIM + tid];
      }
      if(vy1){
        const float* row = vb + (size_t)(y1*WF)*C_DIM;
        if(vx0) g += (1.f-fx)*fy * row[x0*C_DIM + tid];
        if(vx1) g += fx*fy       * row[x1*C_DIM + tid];
      }
      a += attns[h*8+p]*g;
    }
    acc += a;
  }
  const float slot = acc / fmaxf(cnt, 1.f);

  if(!INLINE_Q){
    slots_or_out[(size_t)n*C_DIM + tid] = slot;     // path A: out_proj later
  } else {
    sl[tid] = slot;
    __syncthreads();
    float o = bout[tid] + query[(size_t)n*C_DIM + tid];
    for(int k=0;k<C_DIM;k++)
      o += sl[k]*Wout[k*C_DIM + tid];
    slots_or_out[(size_t)n*C_DIM + tid] = o;
  }
}

// ---------------------------------------------------------------------------
// Path A: out = slots @ Wout + bout + query (residual = ORIGINAL query).
// ---------------------------------------------------------------------------
__global__ void out_proj_kernel(const float* __restrict__ slots,
                                const float* __restrict__ Wout,
                                const float* __restrict__ bout,
                                const float* __restrict__ query,
                                float* __restrict__ out){
  __shared__ float tile[16][C_DIM];
  const int r0  = blockIdx.x * 16;
  const int tid = threadIdx.x;
  #pragma unroll
  for(int r=0;r<16;r++)
    tile[r][tid] = slots[(size_t)(r0+r)*C_DIM + tid];
  __syncthreads();
  float acc[16];
  const float bias = bout[tid];
  #pragma unroll
  for(int r=0;r<16;r++) acc[r]=bias;
  for(int k=0;k<C_DIM;k++){
    const float w = Wout[k*C_DIM + tid];
    #pragma unroll
    for(int r=0;r<16;r++) acc[r] += tile[r][k]*w;
  }
  #pragma unroll
  for(int r=0;r<16;r++){
    const size_t idx = (size_t)(r0+r)*C_DIM + tid;
    out[idx] = acc[r] + query[idx];
  }
}

extern "C" void kernel_launch(void* const* d_in, const int* in_sizes, int n_in,
                              void* d_out, int out_size, void* d_ws, size_t ws_size,
                              hipStream_t stream){
  const float* query     = (const float*)d_in[0];
  const float* query_pos = (const float*)d_in[1];
  const float* value     = (const float*)d_in[2];
  const float* ref       = (const float*)d_in[3];
  const unsigned char* mask = (const unsigned char*)d_in[4];
  const float* Wv   = (const float*)d_in[5];
  const float* bv   = (const float*)d_in[6];
  const float* Wo   = (const float*)d_in[7];
  const float* bo   = (const float*)d_in[8];
  const float* Wa   = (const float*)d_in[9];
  const float* ba   = (const float*)d_in[10];
  const float* Wout = (const float*)d_in[11];
  const float* bout = (const float*)d_in[12];
  float* out = (float*)d_out;

  // workspace layout: [flag(64B pad)] [vproj 4.1MB] [off 4MB] [attnw 2MB] [slots 8MB]
  int*   flag  = (int*)d_ws;
  float* vproj = (float*)((char*)d_ws + 64);
  float* off   = vproj + (size_t)S_CAM*M_VAL*C_DIM;
  float* attnw = off   + (size_t)N_Q*64;
  float* slots = attnw + (size_t)N_Q*32;
  const size_t needA = 64 + sizeof(float)*((size_t)S_CAM*M_VAL*C_DIM
                        + (size_t)N_Q*64 + (size_t)N_Q*32 + (size_t)N_Q*C_DIM);
  const bool pathA = ws_size >= needA;

  sniff_mask_kernel<<<1, 1024, 0, stream>>>(mask, flag);
  value_proj_kernel<<<(S_CAM*M_VAL)/16, 128, 0, stream>>>(value, Wv, bv, vproj);
  if(pathA){
    q_proj_kernel<<<N_Q/16, 128, 0, stream>>>(query, query_pos, Wo, bo, Wa, ba, off, attnw);
    deform_kernel<false><<<N_Q, 128, 0, stream>>>(vproj, off, attnw, query, query_pos,
                                                  Wo, bo, Wa, ba, ref, mask, flag,
                                                  Wout, bout, slots);
    out_proj_kernel<<<N_Q/16, 128, 0, stream>>>(slots, Wout, bout, query, out);
  } else {
    deform_kernel<true><<<N_Q, 128, 0, stream>>>(vproj, nullptr, nullptr, query, query_pos,
                                                 Wo, bo, Wa, ba, ref, mask, flag,
                                                 Wout, bout, out);
  }
}

// Round 3
// 250.560 us; speedup vs baseline: 1.7282x; 1.7282x over previous
//
#include <hip/hip_runtime.h>

#define N_Q   16384
#define C_DIM 128
#define S_CAM 6
#define M_VAL 1400   // 28*50
#define D_Z   8
#define HF    28
#define WF    50
#define QPB   8      // queries per block in the fused kernel

// ---------------------------------------------------------------------------
// Determine how the bool bev_mask was uploaded: 0=uint8, 1=int32, 2=int64.
// Random 0/1 bools: uint8 -> bytes at i%4!=0 ~50% nonzero; int32 -> those are
// zero but i%8==4 bytes ~50% nonzero; int64 -> both groups all zero.
// ---------------------------------------------------------------------------
__global__ void sniff_mask_kernel(const unsigned char* __restrict__ m,
                                  int* __restrict__ flag){
  __shared__ int cntA, cntB;
  if(threadIdx.x==0){ cntA=0; cntB=0; }
  __syncthreads();
  int i = threadIdx.x;
  unsigned char v = m[i];
  if(((i&3)!=0) && v!=0) atomicAdd(&cntA,1);
  if(((i&7)==4) && v!=0) atomicAdd(&cntB,1);
  __syncthreads();
  if(threadIdx.x==0) *flag = (cntA>0) ? 0 : (cntB>0 ? 1 : 2);
}

__device__ __forceinline__ bool mask_any(const unsigned char* __restrict__ mask,
                                         int mflag, size_t mbase){
  if(mflag==0){
    int any=0;
    #pragma unroll
    for(int d=0;d<D_Z;d++) any |= mask[mbase+d];
    return any!=0;
  } else if(mflag==1){
    const int* mp = (const int*)mask;  int any=0;
    #pragma unroll
    for(int d=0;d<D_Z;d++) any |= mp[mbase+d];
    return any!=0;
  } else {
    const long long* mp = (const long long*)mask;  long long any=0;
    #pragma unroll
    for(int d=0;d<D_Z;d++) any |= mp[mbase+d];
    return any!=0;
  }
}

// ---------------------------------------------------------------------------
// v = value @ Wv + bv   (8400 x 128) @ (128 x 128), f32 -> workspace.
// Block = 16 rows, 128 threads (thread = output column), float4 staging.
// ---------------------------------------------------------------------------
__global__ void value_proj_kernel(const float* __restrict__ value,
                                  const float* __restrict__ Wv,
                                  const float* __restrict__ bv,
                                  float* __restrict__ vout){
  __shared__ float tile[16][C_DIM];
  const int r0  = blockIdx.x * 16;
  const int tid = threadIdx.x;
  {
    const float4* src = (const float4*)(value + (size_t)r0*C_DIM);
    float4* dst = (float4*)&tile[0][0];
    #pragma unroll
    for(int i=0;i<4;i++) dst[tid + 128*i] = src[tid + 128*i];
  }
  __syncthreads();
  float acc[16];
  const float bias = bv[tid];
  #pragma unroll
  for(int r=0;r<16;r++) acc[r]=bias;
  for(int k=0;k<C_DIM;k++){
    const float w = Wv[k*C_DIM + tid];
    #pragma unroll
    for(int r=0;r<16;r++) acc[r] += tile[r][k]*w;   // tile[r][k]: LDS broadcast
  }
  #pragma unroll
  for(int r=0;r<16;r++)
    vout[(size_t)(r0+r)*C_DIM + tid] = acc[r];
}

// ---------------------------------------------------------------------------
// Fused: q-projection (offsets + attn softmax) -> deformable bilinear gather
// (float4 channels) -> camera-masked average -> output projection + residual.
// Block = 8 queries x 256 threads. Gather thread = (query, head, 4-channel).
// ---------------------------------------------------------------------------
__global__ __launch_bounds__(256, 8)
void fused_deform_kernel(const float* __restrict__ vproj,
                         const float* __restrict__ query,
                         const float* __restrict__ query_pos,
                         const float* __restrict__ Wo, const float* __restrict__ bo,
                         const float* __restrict__ Wa, const float* __restrict__ ba,
                         const float* __restrict__ ref,
                         const unsigned char* __restrict__ mask,
                         const int* __restrict__ flag,
                         const float* __restrict__ Wout,
                         const float* __restrict__ bout,
                         float* __restrict__ out){
  __shared__ float qs[QPB][C_DIM];
  __shared__ float offs[QPB][64];
  __shared__ float attns[QPB][32];
  __shared__ float logits[QPB][32];
  __shared__ float sl[QPB][C_DIM];
  __shared__ int   activ[QPB][S_CAM];
  __shared__ float cinv[QPB];

  const int tid = threadIdx.x;
  const int n0  = blockIdx.x * QPB;
  const int mflag = flag[0];

  // ---- 1) q = query + query_pos (flat float4: 256 threads x 16B = 4KB) ----
  {
    const float4* qa = (const float4*)(query     + (size_t)n0*C_DIM);
    const float4* qb = (const float4*)(query_pos + (size_t)n0*C_DIM);
    float4 a = qa[tid], b = qb[tid];
    ((float4*)&qs[0][0])[tid] = make_float4(a.x+b.x, a.y+b.y, a.z+b.z, a.w+b.w);
  }
  __syncthreads();

  // ---- 2) offset/attn projections: thread = (qi, col in [0,32)) ----
  {
    const int qi = tid >> 5, col = tid & 31;
    float acc0 = bo[col], acc1 = bo[col+32], acc2 = ba[col];
    for(int k=0;k<C_DIM;k++){
      const float qv = qs[qi][k];
      acc0 += qv * Wo[k*64 + col];
      acc1 += qv * Wo[k*64 + col + 32];
      acc2 += qv * Wa[k*32 + col];
    }
    offs[qi][col]    = acc0;
    offs[qi][col+32] = acc1;
    logits[qi][col]  = acc2;
  }
  if(tid < QPB*S_CAM){                       // camera-hit mask per query
    const int qi = tid / S_CAM, s = tid % S_CAM;
    activ[qi][s] = mask_any(mask, mflag, ((size_t)s*N_Q + (n0+qi))*D_Z) ? 1 : 0;
  }
  __syncthreads();

  if(tid < 32){                              // softmax over P=8: (qi, h)
    const int qi = tid >> 2, h = tid & 3;
    const float* L = &logits[qi][h*8];
    float mx = L[0];
    #pragma unroll
    for(int p=1;p<8;p++) mx = fmaxf(mx, L[p]);
    float e[8], ssum = 0.f;
    #pragma unroll
    for(int p=0;p<8;p++){ e[p] = __expf(L[p]-mx); ssum += e[p]; }
    const float inv = 1.f/ssum;
    #pragma unroll
    for(int p=0;p<8;p++) attns[qi][h*8+p] = e[p]*inv;
  } else if(tid >= 256-QPB){                 // 1/max(cnt,1) per query
    const int qi = tid - (256-QPB);
    int c = 0;
    #pragma unroll
    for(int s=0;s<S_CAM;s++) c += activ[qi][s];
    cinv[qi] = 1.f / fmaxf((float)c, 1.f);
  }
  __syncthreads();

  // ---- 3) gather: thread = (qi, h, c4) ; 4 channels per thread ----
  {
    const int qi = tid >> 5;
    const int l  = tid & 31;
    const int h  = l >> 3;
    const int c4 = l & 7;
    const int n  = n0 + qi;
    const int ch = h*32 + c4*4;

    float ax=0.f, ay=0.f, az=0.f, aw=0.f;
    for(int s=0;s<S_CAM;s++){
      if(!activ[qi][s]) continue;
      const float* rp = ref + ((size_t)s*N_Q + n)*D_Z*2;
      const float* vb = vproj + (size_t)s*M_VAL*C_DIM + ch;
      #pragma unroll
      for(int p=0;p<8;p++){                  // point p <-> z-anchor d=p (P//D==1)
        const float x = (rp[p*2+0] + offs[qi][h*16+p*2+0]*(1.0f/(float)WF))*(float)WF - 0.5f;
        const float y = (rp[p*2+1] + offs[qi][h*16+p*2+1]*(1.0f/(float)HF))*(float)HF - 0.5f;
        const float x0f = floorf(x), y0f = floorf(y);
        const float fx = x - x0f,    fy = y - y0f;
        const int x0 = (int)x0f, y0 = (int)y0f;
        const int x1 = x0+1,     y1 = y0+1;
        const float fvx0 = (x0>=0 && x0<WF) ? 1.f : 0.f;
        const float fvx1 = (x1>=0 && x1<WF) ? 1.f : 0.f;
        const float fvy0 = (y0>=0 && y0<HF) ? 1.f : 0.f;
        const float fvy1 = (y1>=0 && y1<HF) ? 1.f : 0.f;
        const int x0c = min(max(x0,0), WF-1), x1c = min(max(x1,0), WF-1);
        const int y0c = min(max(y0,0), HF-1), y1c = min(max(y1,0), HF-1);
        const float at = attns[qi][h*8+p];
        const float wx0 = (1.f-fx)*fvx0, wx1 = fx*fvx1;
        const float wy0 = (1.f-fy)*fvy0*at, wy1 = fy*fvy1*at;
        const float w00 = wx0*wy0, w01 = wx1*wy0;
        const float w10 = wx0*wy1, w11 = wx1*wy1;
        const float4 v00 = *(const float4*)(vb + (size_t)(y0c*WF + x0c)*C_DIM);
        const float4 v01 = *(const float4*)(vb + (size_t)(y0c*WF + x1c)*C_DIM);
        const float4 v10 = *(const float4*)(vb + (size_t)(y1c*WF + x0c)*C_DIM);
        const float4 v11 = *(const float4*)(vb + (size_t)(y1c*WF + x1c)*C_DIM);
        ax += w00*v00.x + w01*v01.x + w10*v10.x + w11*v11.x;
        ay += w00*v00.y + w01*v01.y + w10*v10.y + w11*v11.y;
        az += w00*v00.z + w01*v01.z + w10*v10.z + w11*v11.z;
        aw += w00*v00.w + w01*v01.w + w10*v10.w + w11*v11.w;
      }
    }
    const float inv = cinv[qi];
    *(float4*)&sl[qi][ch] = make_float4(ax*inv, ay*inv, az*inv, aw*inv);
  }
  __syncthreads();

  // ---- 4) out = slots @ Wout + bout + query (original query residual) ----
  {
    const int qi = tid >> 5, c4 = tid & 31;   // cols 4*c4 .. 4*c4+3
    const int n  = n0 + qi;
    const float4 b4 = *(const float4*)&bout[c4*4];
    const float4 r4 = *(const float4*)&query[(size_t)n*C_DIM + c4*4];
    float ox = b4.x + r4.x, oy = b4.y + r4.y, oz = b4.z + r4.z, ow = b4.w + r4.w;
    for(int k=0;k<C_DIM;k++){
      const float s  = sl[qi][k];
      const float4 w = *(const float4*)&Wout[(size_t)k*C_DIM + c4*4];
      ox += s*w.x; oy += s*w.y; oz += s*w.z; ow += s*w.w;
    }
    *(float4*)&out[(size_t)n*C_DIM + c4*4] = make_float4(ox, oy, oz, ow);
  }
}

extern "C" void kernel_launch(void* const* d_in, const int* in_sizes, int n_in,
                              void* d_out, int out_size, void* d_ws, size_t ws_size,
                              hipStream_t stream){
  const float* query     = (const float*)d_in[0];
  const float* query_pos = (const float*)d_in[1];
  const float* value     = (const float*)d_in[2];
  const float* ref       = (const float*)d_in[3];
  const unsigned char* mask = (const unsigned char*)d_in[4];
  const float* Wv   = (const float*)d_in[5];
  const float* bv   = (const float*)d_in[6];
  const float* Wo   = (const float*)d_in[7];
  const float* bo   = (const float*)d_in[8];
  const float* Wa   = (const float*)d_in[9];
  const float* ba   = (const float*)d_in[10];
  const float* Wout = (const float*)d_in[11];
  const float* bout = (const float*)d_in[12];
  float* out = (float*)d_out;

  // workspace: [flag 64B] [vproj S*M*C f32 = 4.3 MB]
  int*   flag  = (int*)d_ws;
  float* vproj = (float*)((char*)d_ws + 64);

  sniff_mask_kernel<<<1, 1024, 0, stream>>>(mask, flag);
  value_proj_kernel<<<(S_CAM*M_VAL)/16, 128, 0, stream>>>(value, Wv, bv, vproj);
  fused_deform_kernel<<<N_Q/QPB, 256, 0, stream>>>(vproj, query, query_pos,
                                                   Wo, bo, Wa, ba, ref, mask, flag,
                                                   Wout, bout, out);
}

// Round 4
// 210.540 us; speedup vs baseline: 2.0567x; 1.1901x over previous
//
#include <hip/hip_runtime.h>
#include <hip/hip_bf16.h>

#define N_Q   16384
#define C_DIM 128
#define S_CAM 6
#define M_VAL 1400   // 28*50
#define D_Z   8
#define HF    28
#define WF    50
#define QPB   8      // queries per block in the fused kernel

__device__ __forceinline__ float bf2f(unsigned short u){
  return __uint_as_float(((unsigned)u) << 16);
}

// ---------------------------------------------------------------------------
// bev_mask upload format sniffing (0=uint8,1=int32,2=int64): random 0/1 bools
// -> uint8: bytes i%4!=0 ~50% nonzero; int32: those zero, i%8==4 ~50% nonzero;
// int64: both zero. Fused into value_proj (block 0) to save a dispatch.
// ---------------------------------------------------------------------------

// v = value @ Wv + bv (8400x128 @ 128x128) -> bf16 workspace.
// Block = 8 rows, 128 threads (thread = output column).
__global__ void value_proj_kernel(const float* __restrict__ value,
                                  const float* __restrict__ Wv,
                                  const float* __restrict__ bv,
                                  unsigned short* __restrict__ vout16,
                                  const unsigned char* __restrict__ mask,
                                  int* __restrict__ flag){
  __shared__ float tile[8][C_DIM];
  __shared__ int cntA, cntB;
  const int r0  = blockIdx.x * 8;
  const int tid = threadIdx.x;
  if(blockIdx.x==0 && tid==0){ cntA=0; cntB=0; }
  {
    const float4* src = (const float4*)(value + (size_t)r0*C_DIM);
    float4* dst = (float4*)&tile[0][0];
    dst[tid]       = src[tid];
    dst[tid + 128] = src[tid + 128];
  }
  __syncthreads();
  float acc[8];
  const float bias = bv[tid];
  #pragma unroll
  for(int r=0;r<8;r++) acc[r]=bias;
  for(int k=0;k<C_DIM;k++){
    const float w = Wv[k*C_DIM + tid];
    #pragma unroll
    for(int r=0;r<8;r++) acc[r] += tile[r][k]*w;   // tile[r][k]: LDS broadcast
  }
  #pragma unroll
  for(int r=0;r<8;r++)
    vout16[(size_t)(r0+r)*C_DIM + tid] =
        __bfloat16_as_ushort(__float2bfloat16(acc[r]));

  if(blockIdx.x==0){                 // mask-format sniff, piggybacked
    int a=0, b=0;
    for(int i=tid;i<1024;i+=128){
      const unsigned char v = mask[i];
      if(((i&3)!=0) && v) a=1;
      if(((i&7)==4) && v) b=1;
    }
    if(a) atomicOr(&cntA,1);
    if(b) atomicOr(&cntB,1);
    __syncthreads();
    if(tid==0) *flag = cntA ? 0 : (cntB ? 1 : 2);
  }
}

__device__ __forceinline__ bool mask_any(const unsigned char* __restrict__ mask,
                                         int mflag, size_t mbase){
  if(mflag==0){
    int any=0;
    #pragma unroll
    for(int d=0;d<D_Z;d++) any |= mask[mbase+d];
    return any!=0;
  } else if(mflag==1){
    const int* mp = (const int*)mask;  int any=0;
    #pragma unroll
    for(int d=0;d<D_Z;d++) any |= mp[mbase+d];
    return any!=0;
  } else {
    const long long* mp = (const long long*)mask;  long long any=0;
    #pragma unroll
    for(int d=0;d<D_Z;d++) any |= mp[mbase+d];
    return any!=0;
  }
}

// ---------------------------------------------------------------------------
// Fused: q-proj (offsets + attn softmax) -> per-camera precompute of bilinear
// weights/indices in LDS (one lane per (q,h,p)) -> bf16 float4-equivalent
// gather (thread = (q,h,4ch)) -> masked camera average -> out-proj + residual.
// ---------------------------------------------------------------------------
__global__ __launch_bounds__(256, 4)
void fused_deform_kernel(const unsigned short* __restrict__ vb16,
                         const float* __restrict__ query,
                         const float* __restrict__ query_pos,
                         const float* __restrict__ Wo, const float* __restrict__ bo,
                         const float* __restrict__ Wa, const float* __restrict__ ba,
                         const float* __restrict__ ref,
                         const unsigned char* __restrict__ mask,
                         const int* __restrict__ flag,
                         const float* __restrict__ Wout,
                         const float* __restrict__ bout,
                         float* __restrict__ out){
  __shared__ float qs[QPB][C_DIM];          // q staging, reused as slots
  __shared__ float offs[QPB][64];
  __shared__ float attns[QPB][32];
  __shared__ float logits[QPB][32];
  __shared__ float4 swt[QPB][4][8];         // per-s corner weights (attn-scaled)
  __shared__ int4   sidx[QPB][4][8];        // per-s corner row offsets (elements)
  __shared__ int    activ[QPB][S_CAM];
  __shared__ float  cinv[QPB];

  const int tid = threadIdx.x;
  const int n0  = blockIdx.x * QPB;
  const int mflag = flag[0];
  const int qi = tid >> 5;
  const int l  = tid & 31;

  // ---- 1) q = query + query_pos ----
  {
    const float4* qa = (const float4*)(query     + (size_t)n0*C_DIM);
    const float4* qb = (const float4*)(query_pos + (size_t)n0*C_DIM);
    float4 a = qa[tid], b = qb[tid];
    ((float4*)&qs[0][0])[tid] = make_float4(a.x+b.x, a.y+b.y, a.z+b.z, a.w+b.w);
  }
  __syncthreads();

  // ---- 2) offset/attn projections: thread = (qi, col in [0,32)) ----
  {
    const int col = l;
    float acc0 = bo[col], acc1 = bo[col+32], acc2 = ba[col];
    for(int k=0;k<C_DIM;k++){
      const float qv = qs[qi][k];
      acc0 += qv * Wo[k*64 + col];
      acc1 += qv * Wo[k*64 + col + 32];
      acc2 += qv * Wa[k*32 + col];
    }
    offs[qi][col]    = acc0;
    offs[qi][col+32] = acc1;
    logits[qi][col]  = acc2;
  }
  if(tid < QPB*S_CAM){
    const int q2 = tid / S_CAM, s = tid % S_CAM;
    activ[q2][s] = mask_any(mask, mflag, ((size_t)s*N_Q + (n0+q2))*D_Z) ? 1 : 0;
  }
  __syncthreads();

  if(tid < 32){                              // softmax over P=8: (qi2, h)
    const int q2 = tid >> 2, h = tid & 3;
    const float* L = &logits[q2][h*8];
    float mx = L[0];
    #pragma unroll
    for(int p=1;p<8;p++) mx = fmaxf(mx, L[p]);
    float e[8], ssum = 0.f;
    #pragma unroll
    for(int p=0;p<8;p++){ e[p] = __expf(L[p]-mx); ssum += e[p]; }
    const float inv = 1.f/ssum;
    #pragma unroll
    for(int p=0;p<8;p++) attns[q2][h*8+p] = e[p]*inv;
  } else if(tid >= 256-QPB){
    const int q2 = tid - (256-QPB);
    int c = 0;
    #pragma unroll
    for(int s=0;s<S_CAM;s++) c += activ[q2][s];
    cinv[q2] = 1.f / fmaxf((float)c, 1.f);
  }
  __syncthreads();

  // ---- 3) per-camera: precompute weights/indices, then gather ----
  const int gh  = l >> 3;                    // gather thread: head
  const int gc4 = l & 7;                     // 4-channel group
  const int gch = gh*32 + gc4*4;
  const int ph  = l >> 3;                    // precompute thread: head
  const int pp  = l & 7;                     // precompute thread: point
  float ax=0.f, ay=0.f, az=0.f, aw=0.f;

  for(int s=0;s<S_CAM;s++){
    {   // precompute: one lane per (qi, h, p) — exactly 256 lanes
      const float* rp = ref + ((size_t)s*N_Q + (n0+qi))*D_Z*2;
      const float x = (rp[pp*2+0] + offs[qi][ph*16+pp*2+0]*(1.0f/(float)WF))*(float)WF - 0.5f;
      const float y = (rp[pp*2+1] + offs[qi][ph*16+pp*2+1]*(1.0f/(float)HF))*(float)HF - 0.5f;
      const float x0f = floorf(x), y0f = floorf(y);
      const float fx = x - x0f,    fy = y - y0f;
      const int x0 = (int)x0f, y0 = (int)y0f;
      const int x1 = x0+1,     y1 = y0+1;
      const float at = activ[qi][s] ? attns[qi][ph*8+pp] : 0.f;
      const float wx0 = (x0>=0 && x0<WF) ? (1.f-fx) : 0.f;
      const float wx1 = (x1>=0 && x1<WF) ? fx       : 0.f;
      const float wy0 = ((y0>=0 && y0<HF) ? (1.f-fy) : 0.f) * at;
      const float wy1 = ((y1>=0 && y1<HF) ? fy       : 0.f) * at;
      const int x0c = min(max(x0,0), WF-1), x1c = min(max(x1,0), WF-1);
      const int y0c = min(max(y0,0), HF-1), y1c = min(max(y1,0), HF-1);
      swt [qi][ph][pp] = make_float4(wx0*wy0, wx1*wy0, wx0*wy1, wx1*wy1);
      sidx[qi][ph][pp] = make_int4((y0c*WF+x0c)*C_DIM, (y0c*WF+x1c)*C_DIM,
                                   (y1c*WF+x0c)*C_DIM, (y1c*WF+x1c)*C_DIM);
    }
    __syncthreads();
    {   // gather: thread = (qi, h, c4), bf16x4 loads
      const unsigned short* vb = vb16 + (size_t)s*M_VAL*C_DIM + gch;
      #pragma unroll
      for(int p=0;p<8;p++){
        const int4   id = sidx[qi][gh][p];
        const float4 w  = swt [qi][gh][p];
        const ushort4 v00 = *(const ushort4*)(vb + id.x);
        const ushort4 v01 = *(const ushort4*)(vb + id.y);
        const ushort4 v10 = *(const ushort4*)(vb + id.z);
        const ushort4 v11 = *(const ushort4*)(vb + id.w);
        ax += w.x*bf2f(v00.x) + w.y*bf2f(v01.x) + w.z*bf2f(v10.x) + w.w*bf2f(v11.x);
        ay += w.x*bf2f(v00.y) + w.y*bf2f(v01.y) + w.z*bf2f(v10.y) + w.w*bf2f(v11.y);
        az += w.x*bf2f(v00.z) + w.y*bf2f(v01.z) + w.z*bf2f(v10.z) + w.w*bf2f(v11.z);
        aw += w.x*bf2f(v00.w) + w.y*bf2f(v01.w) + w.z*bf2f(v10.w) + w.w*bf2f(v11.w);
      }
    }
    __syncthreads();
  }

  // ---- 4) slots (reuse qs) + out-proj + residual ----
  {
    const float inv = cinv[qi];
    *(float4*)&qs[qi][gch] = make_float4(ax*inv, ay*inv, az*inv, aw*inv);
  }
  __syncthreads();
  {
    const int c4 = l;                        // cols 4*c4 .. 4*c4+3
    const int n  = n0 + qi;
    const float4 b4 = *(const float4*)&bout[c4*4];
    const float4 r4 = *(const float4*)&query[(size_t)n*C_DIM + c4*4];
    float ox = b4.x + r4.x, oy = b4.y + r4.y, oz = b4.z + r4.z, ow = b4.w + r4.w;
    for(int k=0;k<C_DIM;k++){
      const float sv = qs[qi][k];
      const float4 w = *(const float4*)&Wout[(size_t)k*C_DIM + c4*4];
      ox += sv*w.x; oy += sv*w.y; oz += sv*w.z; ow += sv*w.w;
    }
    *(float4*)&out[(size_t)n*C_DIM + c4*4] = make_float4(ox, oy, oz, ow);
  }
}

extern "C" void kernel_launch(void* const* d_in, const int* in_sizes, int n_in,
                              void* d_out, int out_size, void* d_ws, size_t ws_size,
                              hipStream_t stream){
  const float* query     = (const float*)d_in[0];
  const float* query_pos = (const float*)d_in[1];
  const float* value     = (const float*)d_in[2];
  const float* ref       = (const float*)d_in[3];
  const unsigned char* mask = (const unsigned char*)d_in[4];
  const float* Wv   = (const float*)d_in[5];
  const float* bv   = (const float*)d_in[6];
  const float* Wo   = (const float*)d_in[7];
  const float* bo   = (const float*)d_in[8];
  const float* Wa   = (const float*)d_in[9];
  const float* ba   = (const float*)d_in[10];
  const float* Wout = (const float*)d_in[11];
  const float* bout = (const float*)d_in[12];
  float* out = (float*)d_out;

  // workspace: [flag 64B] [vproj bf16 S*M*C = 2.15 MB]
  int* flag = (int*)d_ws;
  unsigned short* vb16 = (unsigned short*)((char*)d_ws + 64);

  value_proj_kernel<<<(S_CAM*M_VAL)/8, 128, 0, stream>>>(value, Wv, bv, vb16, mask, flag);
  fused_deform_kernel<<<N_Q/QPB, 256, 0, stream>>>(vb16, query, query_pos,
                                                   Wo, bo, Wa, ba, ref, mask, flag,
                                                   Wout, bout, out);
}